// Round 4
// baseline (794.380 us; speedup 1.0000x reference)
//
#include <hip/hip_runtime.h>

#define B_   4
#define L_   8192
#define D_   2048
#define H_   32
#define WIN_ 1024
#define U_   512      // tokens per (window, parity) slice
#define PAD_ 68       // 64 + 4 pad: row->bank shift of 4 keeps b128 reads near floor
#define QSC  0.125f   // score scale folded into Q

// cross-lane add via DPP on the VALU pipe
template <int CTRL>
__device__ __forceinline__ float dpp_add(float v) {
    int s = __builtin_amdgcn_update_dpp(0, __builtin_bit_cast(int, v), CTRL, 0xf, 0xf, true);
    return v + __builtin_bit_cast(float, s);
}
// sum over an aligned 8-lane group: xor1, xor2, then row_half_mirror.
// HW-verified in previous rounds.
__device__ __forceinline__ float red8(float v) {
    v = dpp_add<0xB1>(v);    // quad_perm [1,0,3,2]  (xor 1)
    v = dpp_add<0x4E>(v);    // quad_perm [2,3,0,1]  (xor 2)
    v = dpp_add<0x141>(v);   // row_half_mirror      (xor 4 after quad uniformity)
    return v;
}

// 8-dim dot as two independent fma chains (ILP) + combine
__device__ __forceinline__ float dot8(const float4& a0, const float4& a1,
                                      const float4& b0, const float4& b1) {
    float s = a0.x * b0.x, t = a0.y * b0.y;
    s = fmaf(a0.z, b0.z, s); t = fmaf(a0.w, b0.w, t);
    s = fmaf(a1.x, b1.x, s); t = fmaf(a1.y, b1.y, t);
    s = fmaf(a1.z, b1.z, s); t = fmaf(a1.w, b1.w, t);
    return s + t;
}

__device__ __forceinline__ void fma4(float4& a, float s, const float4& b) {
    a.x = fmaf(s, b.x, a.x); a.y = fmaf(s, b.y, a.y);
    a.z = fmaf(s, b.z, a.z); a.w = fmaf(s, b.w, a.w);
}

__device__ __forceinline__ float4 mul4(const float4& a, float s) {
    return make_float4(a.x * s, a.y * s, a.z * s, a.w * s);
}

// K1: one block per (b, win, parity, head). 1024 threads = 128 query-slots x
// 8 lanes (8 head-dims each); 4 in-block iterations cover the 512 queries.
//
// GROUP-MAJOR QUERY MAPPING (the round-4 change): round-3 was LDS-bound
// (~428 us of modeled LDS-pipe time vs 442 us measured; conflicts 6.2e7).
// With u = wave + 16*j + 128*qq, a wave's 8 query-slots satisfy:
//   u & 15  == wave  (uniform)  -> rate-5 key rows wave-uniform (32 visits)
//   u >> 7  == qq    (uniform), u & 7 uniform -> rate-4 rows wave-uniform (16)
// Wave-uniform rows mean all 8 slots read IDENTICAL byte addresses ->
// LDS broadcast: ~2 bank passes per b128 instead of 8+ for the two biggest
// rates. Rates 1-3 unchanged. Modeled LDS pipe ~240 us < VALU ~296 us.
// Pure permutation of slot->query: correctness invariant.
__global__ __launch_bounds__(1024)
void ddattn_k1(const float* __restrict__ x, float* __restrict__ out,
               float* __restrict__ den) {
    const int bid = blockIdx.x;
    const int h   = bid & 31;
    const int p   = (bid >> 5) & 1;
    const int win = (bid >> 6) & 7;
    const int b   = bid >> 9;

    __shared__ float Xs[U_ * PAD_];
    const int t0 = win * WIN_;
    const float* xb = x + ((size_t)b * L_ + (size_t)(t0 + p)) * D_ + h * 64;

    for (int idx = threadIdx.x; idx < U_ * 16; idx += 1024) {
        const int row = idx >> 4, c = idx & 15;
        *(float4*)(&Xs[row * PAD_ + c * 4]) =
            *(const float4*)(xb + (size_t)row * (2 * D_) + c * 4);
    }
    __syncthreads();

    const int lane8 = threadIdx.x & 7;   // 8-dim slice within the head
    const int slot  = threadIdx.x >> 3;  // query slot 0..127
    const int off   = lane8 * 8;         // dword offset (16B aligned)
    const int wv    = slot >> 3;         // wave id 0..15
    const int j8    = slot & 7;          // slot-in-wave 0..7

#pragma unroll 1
    for (int qq = 0; qq < 4; qq++) {
        const int u = wv + 16 * j8 + 128 * qq;   // group-major mapping

        // acc starts as the unscaled Qu (rate 0: probs==1 -> out += x);
        // Qs = Qu/8 folds the score scale; rate-0 den = exp(Qs . Qu).
        float4 acc0 = *(const float4*)(&Xs[u * PAD_ + off]);
        float4 acc1 = *(const float4*)(&Xs[u * PAD_ + off + 4]);
        const float4 Qs0 = mul4(acc0, QSC), Qs1 = mul4(acc1, QSC);
        float dn = __expf(red8(dot8(Qs0, Qs1, acc0, acc1)));

        // rates 1..5: group base ub, stride step, cnt keys
#pragma unroll
        for (int i = 1; i <= 5; i++) {
            const int step = 1 << (i - 1), cnt = 1 << i;
            const int ub = ((u >> (2 * i - 1)) << (2 * i - 1)) | (u & (step - 1));
            const float* ptr = &Xs[ub * PAD_ + off];
            float4 E0 = make_float4(0, 0, 0, 0), E1 = E0;
            float D = 0.f;
#pragma unroll 4
            for (int k = 0; k < cnt; k++) {
                const float4 R0 = *(const float4*)(ptr);
                const float4 R1 = *(const float4*)(ptr + 4);
                ptr += step * PAD_;
                const float e = __expf(red8(dot8(Qs0, Qs1, R0, R1)));
                D += e;
                fma4(E0, e, R0); fma4(E1, e, R1);
            }
            dn += D;
            const float inv = 1.0f / D;
            fma4(acc0, inv, E0); fma4(acc1, inv, E1);
        }

        // write back (8 lanes x 32B contiguous per token -> coalesced 256B/slot)
        const int t = t0 + 2 * u + p;
        float* op = out + ((size_t)b * L_ + t) * D_ + h * 64 + off;
        *(float4*)op = acc0; *(float4*)(op + 4) = acc1;
        if (lane8 == 0) den[((size_t)b * L_ + t) * H_ + h] = dn;
    }
}

// K2a: in-place den -> softmax weights over heads, one token per thread.
// 4 MB read + 4 MB write, ~10 us. Separating this from the 512 MB stream
// lets K2b run barrier-free at BW roofline (and tells us whether the ~340 us
// "K2 share" was real kernel time or fixed harness overhead).
__global__ __launch_bounds__(256)
void ddattn_k2a(float* __restrict__ den) {
    const int t = blockIdx.x * 256 + threadIdx.x;   // 32768 tokens
    float* dp = den + (size_t)t * H_;
    float4 v[8];
    float mx = -3.4e38f;
#pragma unroll
    for (int i = 0; i < 8; i++) {
        v[i] = *(float4*)(dp + i * 4);
        mx = fmaxf(mx, fmaxf(fmaxf(v[i].x, v[i].y), fmaxf(v[i].z, v[i].w)));
    }
    float s = 0.f;
#pragma unroll
    for (int i = 0; i < 8; i++) {
        v[i].x = __expf(v[i].x - mx); v[i].y = __expf(v[i].y - mx);
        v[i].z = __expf(v[i].z - mx); v[i].w = __expf(v[i].w - mx);
        s += v[i].x + v[i].y + v[i].z + v[i].w;
    }
    const float inv = 1.f / s;
#pragma unroll
    for (int i = 0; i < 8; i++) {
        v[i].x *= inv; v[i].y *= inv; v[i].z *= inv; v[i].w *= inv;
        *(float4*)(dp + i * 4) = v[i];
    }
}

// K2b: pure streaming RMW: out[f4 idx] *= w[idx>>4]. idx>>4 == token*32 + h
// exactly (512 float4 per token = 32 heads x 16 float4). 2048 blocks x 256
// threads = fully resident; each block owns a contiguous 128 KB span.
__global__ __launch_bounds__(256)
void ddattn_k2b(float* __restrict__ out, const float* __restrict__ w) {
    const size_t base = (size_t)blockIdx.x * 8192 + threadIdx.x;
    float4* o4 = (float4*)out;
#pragma unroll 4
    for (int c = 0; c < 32; c++) {
        const size_t idx = base + (size_t)c * 256;
        const float ww = w[idx >> 4];
        float4 vv = o4[idx];
        vv.x *= ww; vv.y *= ww; vv.z *= ww; vv.w *= ww;
        o4[idx] = vv;
    }
}

extern "C" void kernel_launch(void* const* d_in, const int* in_sizes, int n_in,
                              void* d_out, int out_size, void* d_ws, size_t ws_size,
                              hipStream_t stream) {
    const float* x = (const float*)d_in[0];
    float* out = (float*)d_out;
    float* den = (float*)d_ws;  // B*L*H fp32 = 4 MB scratch (reused in-place for w)

    ddattn_k1<<<dim3(B_ * (L_ / WIN_) * 2 * H_), dim3(1024), 0, stream>>>(x, out, den);
    ddattn_k2a<<<dim3(B_ * L_ / 256), dim3(256), 0, stream>>>(den);
    ddattn_k2b<<<dim3(2048), dim3(256), 0, stream>>>(out, den);
}